// Round 3
// baseline (714.848 us; speedup 1.0000x reference)
//
#include <hip/hip_runtime.h>
#include <hip/hip_bf16.h>
#include <cfloat>

// Problem constants (GeoTokenizer): B=8, N=4096 -> M=32768 rows
#define M_ROWS 32768
#define DIM    768
#define VOCABN 4096
#define HIDN   128
#define QB     64      // (fallback) queries per argmin block
#define CAP    32      // (fallback) candidate buffer per query
#define MARGIN 2.0f    // 2*delta; |approx-exact| bound delta=1.0 (validated R2-R4)

// Phase-1 GEMM tiling (256x256 deep-pipelined)
#define BM2 256
#define BN2 256
#define NCB2 (VOCABN / BN2)  // 16 code-blocks of 256
#define CAP2 6               // stored candidates per (query, code-block)
#define NKC  (DIM / 32)      // 24 k-chunks of 32

typedef __attribute__((ext_vector_type(8))) short bf16x8;  // MFMA A/B frag
typedef __attribute__((ext_vector_type(4))) float f32x4;   // MFMA C/D frag

static __device__ __forceinline__ short f2b(float x) {
    __hip_bfloat16 h = __float2bfloat16(x);   // RNE
    return *reinterpret_cast<short*>(&h);
}

// async global->LDS, 16B per lane; LDS dest is wave-uniform base + lane*16
static __device__ __forceinline__ void gload_lds16(const void* g, void* l) {
    __builtin_amdgcn_global_load_lds(
        (const __attribute__((address_space(1))) unsigned int*)g,
        (__attribute__((address_space(3))) unsigned int*)l, 16, 0, 0);
}

// Fragment-unit indexing (16 B units of 8 bf16), GLOBAL row-tile rt = row>>4:
//   A: unit = (rt*NKC + kc)*64 + lane
//      holds comb[row = rt*16 + (lane&15)][k = kc*32 + (lane>>4)*8 ..+8]
//   B: unit = (ct*NKC + kc)*64 + lane   (ct = code>>4)

// ---------------------------------------------------------------------------
// Kernel 1: fused two-branch MLP encoder (fp32 exact). 32 rows/block.
// write16: emits comb16 in A-FRAGMENT order (scattered shorts, L2-combined).
// ---------------------------------------------------------------------------
__global__ __launch_bounds__(256) void encode_kernel(
    const float* __restrict__ coords, const float* __restrict__ feats,
    const float* __restrict__ Ws1, const float* __restrict__ bs1,
    const float* __restrict__ Ws2, const float* __restrict__ bs2,
    const float* __restrict__ Wf1, const float* __restrict__ bf1,
    const float* __restrict__ Wf2, const float* __restrict__ bf2,
    float* __restrict__ comb, short* __restrict__ comb16f, int write16)
{
    __shared__ float hs[32][HIDN];
    __shared__ float hf[32][HIDN];
    const int row0 = blockIdx.x * 32;
    const int t = threadIdx.x;

    #pragma unroll
    for (int k = 0; k < 16; ++k) {
        const int idx = t + k * 256;
        const int r = idx >> 7;
        const int j = idx & 127;
        const int row = row0 + r;
        const float c0 = coords[row * 2 + 0];
        const float c1 = coords[row * 2 + 1];
        float vs = fmaf(c0, Ws1[j], fmaf(c1, Ws1[HIDN + j], bs1[j]));
        hs[r][j] = fmaxf(vs, 0.0f);
        float vf = bf1[j];
        #pragma unroll
        for (int i = 0; i < 10; ++i)
            vf = fmaf(feats[row * 10 + i], Wf1[i * HIDN + j], vf);
        hf[r][j] = fmaxf(vf, 0.0f);
    }
    __syncthreads();

    float acc[3][32];
    #pragma unroll
    for (int dd = 0; dd < 3; ++dd) {
        const float base = bs2[t + dd * 256] + bf2[t + dd * 256];
        #pragma unroll
        for (int r = 0; r < 32; ++r) acc[dd][r] = base;
    }

    for (int jq = 0; jq < 32; ++jq) {
        float ws[3][4], wf[3][4];
        #pragma unroll
        for (int dd = 0; dd < 3; ++dd) {
            const int d = t + dd * 256;
            #pragma unroll
            for (int jj = 0; jj < 4; ++jj) {
                ws[dd][jj] = Ws2[(jq * 4 + jj) * DIM + d];
                wf[dd][jj] = Wf2[(jq * 4 + jj) * DIM + d];
            }
        }
        #pragma unroll
        for (int r = 0; r < 32; ++r) {
            const float4 h4s = *(const float4*)&hs[r][jq * 4];
            const float4 h4f = *(const float4*)&hf[r][jq * 4];
            #pragma unroll
            for (int dd = 0; dd < 3; ++dd) {
                float a = acc[dd][r];
                a = fmaf(h4s.x, ws[dd][0], a);
                a = fmaf(h4s.y, ws[dd][1], a);
                a = fmaf(h4s.z, ws[dd][2], a);
                a = fmaf(h4s.w, ws[dd][3], a);
                a = fmaf(h4f.x, wf[dd][0], a);
                a = fmaf(h4f.y, wf[dd][1], a);
                a = fmaf(h4f.z, wf[dd][2], a);
                a = fmaf(h4f.w, wf[dd][3], a);
                acc[dd][r] = a;
            }
        }
    }

    const int qt = row0 >> 7;   // 128-row group (qt*8+it == row>>4, global rt)
    #pragma unroll
    for (int dd = 0; dd < 3; ++dd) {
        const int d = t + dd * 256;
        const int kc = d >> 5, kg = (d >> 3) & 3, jj = d & 7;
        #pragma unroll
        for (int r = 0; r < 32; ++r) {
            const int row = row0 + r;
            const float v = acc[dd][r];
            comb[(size_t)row * DIM + d] = v;
            if (write16) {
                const int it = (row >> 4) & 7, n = row & 15;
                const size_t unit = ((size_t)(qt * 8 + it) * NKC + kc) * 64 + kg * 16 + n;
                comb16f[unit * 8 + jj] = f2b(v);
            }
        }
    }
}

// ---------------------------------------------------------------------------
// Kernel 2: c_sq (fp32) + bf16 codebook conversion.
// swizzled=1 -> B-fragment order (main path); 0 -> row-major (fallback path).
// ---------------------------------------------------------------------------
__global__ __launch_bounds__(64) void csq_cvt_kernel(
    const float* __restrict__ codebook, float* __restrict__ csq,
    short* __restrict__ outb, int swizzled)
{
    const int v = blockIdx.x;
    const int l = threadIdx.x;
    float s = 0.0f;
    #pragma unroll
    for (int k = 0; k < DIM / 64; ++k) {
        const float x = codebook[(size_t)v * DIM + l + k * 64];
        if (!swizzled) outb[(size_t)v * DIM + l + k * 64] = f2b(x);
        s = fmaf(x, x, s);
    }
    #pragma unroll
    for (int off = 32; off >= 1; off >>= 1)
        s += __shfl_down(s, off);
    if (l == 0) csq[v] = s;

    if (swizzled) {
        const int cb = v >> 7, jt = (v >> 4) & 7, n = v & 15;
        for (int u = l; u < 96; u += 64) {      // 24 kc x 4 kg
            const int kc = u >> 2, kg = u & 3;
            const float* src = codebook + (size_t)v * DIM + kc * 32 + kg * 8;
            bf16x8 f;
            #pragma unroll
            for (int j = 0; j < 8; ++j) f[j] = f2b(src[j]);
            const size_t unit = ((size_t)(cb * 8 + jt) * NKC + kc) * 64 + kg * 16 + n;
            *(bf16x8*)(outb + unit * 8) = f;
        }
    }
}

// ---------------------------------------------------------------------------
// Kernel 3 (phase 1): 256x256-tile MFMA GEMM, deep-pipelined LDS staging.
// 8 waves (2x4), wave tile 128x64. Operands pre-swizzled in fragment order
// -> global_load_lds with LINEAR LDS dest is bank-conflict-free.
// R3: 2-D chunked XCD mapping. R2's cb-pair remap was null because BOTH
// mappings give each XCD 16 concurrent qt's (6.8 MB working set -> L2
// thrash -> ~4000cy avg load latency, latency-bound feed). Now each XCD's
// 32 concurrent blocks form a 4qt x 8cb chunk:
//   - working set/XCD = 4 A-tiles (1.5 MB) + 8 B-tiles (3.1 MB), and the
//     kc-lockstep instantaneous set is ~200 KB -> L2-hit feed (~300 cyc),
//     hidden by the existing depth-3 prefetch
//   - cb-group h = xcd&1 is FIXED across rounds -> B tiles L2-resident
//     for the whole dispatch
// Bijective: 2048 = 8 XCD x 8 rounds x 32 slots. Math per block unchanged
// -> distances bitwise identical.
// ---------------------------------------------------------------------------
__global__ __launch_bounds__(512, 2) void vq_phase1_kernel(
    const short* __restrict__ comb16f, const short* __restrict__ cbf,
    const float* __restrict__ csq,
    float* __restrict__ lmin_g, int* __restrict__ lbidx_g,
    int* __restrict__ lcnt_g, int* __restrict__ lci_g)
{
    __shared__ __align__(16) char smem[4 * 32768];   // 128 KB, 4 K-step buffers

    const int t = threadIdx.x;
    const int w = t >> 6, l = t & 63;
    const int lm = l & 15, quad = l >> 4;
    const int wr = w >> 2, wc = w & 3;           // 2 x 4 wave grid

    // 2-D chunked XCD mapping (see header comment)
    const int lin = blockIdx.y * (int)gridDim.x + blockIdx.x;
    const int x  = lin & 7;                      // XCD (round-robin assumption)
    const int s_ = (lin >> 3) & 31;              // slot within XCD
    const int r_ = lin >> 8;                     // round (1 block/CU resident)
    const int g  = r_ * 4 + (x >> 1);            // qt-group 0..31
    const int h  = x & 1;                        // cb-group 0..1 (fixed per XCD)
    const int qt = g * 4 + (s_ >> 3);            // 0..127
    const int cb = h * 8 + (s_ & 7);             // 0..15
    const int q0 = qt * BM2;

    // staging: wave w owns frag-sets s = w*4 .. w*4+3 (s<16: A rt=s; else B jt=s-16)
    const short* gsrc[4];
    int doff[4];
    #pragma unroll
    for (int k = 0; k < 4; ++k) {
        const int s = w * 4 + k;
        if (s < 16) {
            gsrc[k] = comb16f + (((size_t)(qt * 16 + s) * NKC) * 64 + l) * 8;
            doff[k] = s * 1024;
        } else {
            gsrc[k] = cbf + (((size_t)(cb * 16 + (s - 16)) * NKC) * 64 + l) * 8;
            doff[k] = 16384 + (s - 16) * 1024;
        }
    }

    f32x4 acc[8][4];
    #pragma unroll
    for (int i = 0; i < 8; ++i)
        #pragma unroll
        for (int j = 0; j < 4; ++j) acc[i][j] = (f32x4){0.f, 0.f, 0.f, 0.f};

    // one STAGE = this wave's 4 frag-sets (4 KB) for K-step kc into buf kc&3
    #define STAGE(kc) do {                                                      \
        char* _d = smem + ((kc) & 3) * 32768;                                   \
        _Pragma("unroll")                                                       \
        for (int _k = 0; _k < 4; ++_k)                                          \
            gload_lds16(gsrc[_k] + (size_t)(kc) * 512, _d + doff[_k]);          \
    } while (0)

    // prologue: prefetch steps 0,1,2 (12 loads); wait own step-0 loads (8 left)
    STAGE(0); STAGE(1); STAGE(2);
    asm volatile("s_waitcnt vmcnt(8)" ::: "memory");
    __builtin_amdgcn_sched_barrier(0);
    __builtin_amdgcn_s_barrier();
    __builtin_amdgcn_sched_barrier(0);

    #pragma unroll
    for (int kc = 0; kc < NKC; ++kc) {
        // ds_reads first (critical path), then DMA staging issue (m201 order)
        const char* buf = smem + (kc & 3) * 32768;
        bf16x8 a[8], b[4];
        #pragma unroll
        for (int i = 0; i < 8; ++i)
            a[i] = *(const bf16x8*)(buf + (wr * 8 + i) * 1024 + l * 16);
        #pragma unroll
        for (int j = 0; j < 4; ++j)
            b[j] = *(const bf16x8*)(buf + 16384 + (wc * 4 + j) * 1024 + l * 16);
        if (kc + 3 < NKC) STAGE(kc + 3);
        __builtin_amdgcn_s_setprio(1);
        #pragma unroll
        for (int i = 0; i < 8; ++i)
            #pragma unroll
            for (int j = 0; j < 4; ++j)
                acc[i][j] = __builtin_amdgcn_mfma_f32_16x16x32_bf16(
                    a[i], b[j], acc[i][j], 0, 0, 0);
        __builtin_amdgcn_s_setprio(0);
        if (kc < NKC - 1) {
            // ensure step kc+1's staging landed (all waves): each wave waits
            // its own loads, then barrier. Steady state leaves kc+2,kc+3 in
            // flight (8 loads) -- never drain to 0 mid-loop.
            if (kc <= NKC - 4)      asm volatile("s_waitcnt vmcnt(8)" ::: "memory");
            else if (kc == NKC - 3) asm volatile("s_waitcnt vmcnt(4)" ::: "memory");
            else                    asm volatile("s_waitcnt vmcnt(0)" ::: "memory");
            __builtin_amdgcn_sched_barrier(0);
            __builtin_amdgcn_s_barrier();
            __builtin_amdgcn_sched_barrier(0);
        }
    }
    #undef STAGE

    // ---- epilogue (reuses LDS buffer 0 region; safe: buf0 last read at kc=20,
    // all waves are past two barriers since) ----
    float* s_wmin = (float*)smem;               // [4][256]  4 KB
    int*   s_widx = (int*)(smem + 4096);        // [4][256]  4 KB
    float* s_thr  = (float*)(smem + 8192);      // [256]     1 KB
    int*   s_cnt  = (int*)(smem + 9216);        // [256]     1 KB
    int*   s_ci   = (int*)(smem + 10240);       // [256][CAP2] 6 KB

    __syncthreads();
    if (t < BM2) s_cnt[t] = 0;

    const int cbase = cb * BN2 + wc * 64;
    float cs[4];
    #pragma unroll
    for (int j = 0; j < 4; ++j) cs[j] = csq[cbase + j * 16 + lm];
    #pragma unroll
    for (int i = 0; i < 8; ++i)
        #pragma unroll
        for (int j = 0; j < 4; ++j)
            #pragma unroll
            for (int r = 0; r < 4; ++r)
                acc[i][j][r] = fmaf(-2.0f, acc[i][j][r], cs[j]);

    // per-query (i,r) min/argmin over j-tiles then over 16 lanes of the quad
    #pragma unroll
    for (int i = 0; i < 8; ++i)
        #pragma unroll
        for (int r = 0; r < 4; ++r) {
            float m = acc[i][0][r];
            int mi = cbase + 0 * 16 + lm;
            #pragma unroll
            for (int j = 1; j < 4; ++j) {
                const float d = acc[i][j][r];
                const int ci = cbase + j * 16 + lm;
                if (d < m || (d == m && ci < mi)) { m = d; mi = ci; }
            }
            #pragma unroll
            for (int off = 1; off <= 8; off <<= 1) {   // stays within quad
                const float om = __shfl_xor(m, off);
                const int oi = __shfl_xor(mi, off);
                if (om < m || (om == m && oi < mi)) { m = om; mi = oi; }
            }
            if (lm == 0) {
                const int qloc = wr * 128 + i * 16 + quad * 4 + r;
                s_wmin[wc * 256 + qloc] = m;
                s_widx[wc * 256 + qloc] = mi;
            }
        }
    __syncthreads();

    if (t < BM2) {
        float bm = s_wmin[t];
        int bi = s_widx[t];
        #pragma unroll
        for (int g2 = 1; g2 < 4; ++g2) {
            const float v = s_wmin[g2 * 256 + t];
            const int ii = s_widx[g2 * 256 + t];
            if (v < bm || (v == bm && ii < bi)) { bm = v; bi = ii; }
        }
        const size_t base = (size_t)cb * M_ROWS + (q0 + t);   // [cb][q] coalesced
        lmin_g[base] = bm;
        lbidx_g[base] = bi;
        s_thr[t] = bm + MARGIN;
    }
    __syncthreads();

    // candidate pass: push everything within margin of the block-local min
    #pragma unroll
    for (int i = 0; i < 8; ++i)
        #pragma unroll
        for (int r = 0; r < 4; ++r) {
            const int qloc = wr * 128 + i * 16 + quad * 4 + r;
            const float thr = s_thr[qloc];
            #pragma unroll
            for (int j = 0; j < 4; ++j) {
                const float d = acc[i][j][r];
                if (d <= thr) {
                    const int p = atomicAdd(&s_cnt[qloc], 1);
                    if (p < CAP2) s_ci[qloc * CAP2 + p] = cbase + j * 16 + lm;
                }
            }
        }
    __syncthreads();

    if (t < BM2) {
        const size_t base = (size_t)cb * M_ROWS + (q0 + t);
        int n = s_cnt[t];
        if (n > CAP2) n = CAP2;
        lcnt_g[base] = n;
        for (int p = 0; p < n; ++p)
            lci_g[base * CAP2 + p] = s_ci[t * CAP2 + p];
    }
}

// ---------------------------------------------------------------------------
// Kernel 4 (phase 2): G = min of 16 local mins; select cbs with lmin<=G+MARGIN
// (provable superset); exact fp32 re-rank of their anchors+candidates; fused
// gather. One wave per query; 4 queries per block.
// ---------------------------------------------------------------------------
#define P2CAP 48
__global__ __launch_bounds__(256) void vq_phase2_kernel(
    const float* __restrict__ comb32, const float* __restrict__ codebook,
    const float* __restrict__ csq,
    const float* __restrict__ lmin_g, const int* __restrict__ lbidx_g,
    const int* __restrict__ lcnt_g, const int* __restrict__ lci_g,
    float* __restrict__ out_tok_f, float* __restrict__ out_q)
{
    __shared__ int s2n[4];
    __shared__ int s2c[4][P2CAP];
    const int t = threadIdx.x, w = t >> 6, l = t & 63;
    const int q = blockIdx.x * 4 + w;
    if (l == 0) s2n[w] = 0;                 // wave-local; LDS ops in-order

    const size_t base = (size_t)l * M_ROWS + q;   // lane l = code-block l
    const float v = (l < NCB2) ? lmin_g[base] : FLT_MAX;
    float g = v;
    #pragma unroll
    for (int off = 1; off <= 32; off <<= 1)
        g = fminf(g, __shfl_xor(g, off));
    const float thr = g + MARGIN;

    if (l < NCB2 && v <= thr) {
        int p = atomicAdd(&s2n[w], 1);
        if (p < P2CAP) s2c[w][p] = lbidx_g[base];   // anchor (cb-local argmin)
        int n = lcnt_g[base];
        if (n > CAP2) n = CAP2;
        for (int e = 0; e < n; ++e) {
            p = atomicAdd(&s2n[w], 1);
            if (p < P2CAP) s2c[w][p] = lci_g[base * CAP2 + e];
        }
    }
    __syncthreads();

    int ns = s2n[w];
    if (ns > P2CAP) ns = P2CAP;
    float bestd = FLT_MAX;
    int bestc = 0x7fffffff;
    const float4* xr = (const float4*)(comb32 + (size_t)q * DIM);
    for (int e = 0; e < ns; ++e) {
        const int c = s2c[w][e];
        const float4* cr = (const float4*)(codebook + (size_t)c * DIM);
        float dot = 0.0f;
        #pragma unroll
        for (int k = 0; k < 3; ++k) {
            const float4 x = xr[l + 64 * k];
            const float4 y = cr[l + 64 * k];
            dot = fmaf(x.x, y.x, fmaf(x.y, y.y, fmaf(x.z, y.z, fmaf(x.w, y.w, dot))));
        }
        #pragma unroll
        for (int off = 1; off <= 32; off <<= 1)
            dot += __shfl_xor(dot, off);     // bitwise-identical in all lanes
        const float d = fmaf(-2.0f, dot, csq[c]);
        if (d < bestd || (d == bestd && c < bestc)) { bestd = d; bestc = c; }
    }
    if (l == 0) out_tok_f[q] = (float)bestc;
    const float4* cr = (const float4*)(codebook + (size_t)bestc * DIM);
    float4* o4 = (float4*)(out_q + (size_t)q * DIM);
    #pragma unroll
    for (int k = 0; k < 3; ++k) o4[l + 64 * k] = cr[l + 64 * k];
}

// ===========================================================================
// FALLBACK PATH (R2, proven): used only if ws_size is too small.
// ===========================================================================
__global__ __launch_bounds__(256) void argmin_mfma_kernel(
    const float* __restrict__ comb, const float* __restrict__ codebook,
    const short* __restrict__ cbb, const float* __restrict__ csq,
    float* __restrict__ out_tok_f, int* __restrict__ tok_i)
{
    __shared__ int s_cnt[QB];
    __shared__ int s_cand[QB][CAP];

    const int t = threadIdx.x;
    const int w = t >> 6;
    const int l = t & 63;
    const int lm = l & 15;
    const int quad = l >> 4;
    const int q0 = blockIdx.x * QB;

    for (int i = t; i < QB; i += 256) s_cnt[i] = 0;
    __syncthreads();

    bf16x8 a_reg[24];
    {
        const int qa = q0 + w * 16 + lm;
        const float* ap = comb + (size_t)qa * DIM + quad * 8;
        #pragma unroll
        for (int kc = 0; kc < 24; ++kc) {
            const float4 lo = *(const float4*)(ap + kc * 32);
            const float4 hi = *(const float4*)(ap + kc * 32 + 4);
            bf16x8 f;
            f[0] = f2b(lo.x); f[1] = f2b(lo.y); f[2] = f2b(lo.z); f[3] = f2b(lo.w);
            f[4] = f2b(hi.x); f[5] = f2b(hi.y); f[6] = f2b(hi.z); f[7] = f2b(hi.w);
            a_reg[kc] = f;
        }
    }

    const short* bp = cbb + (size_t)lm * DIM + quad * 8;
    float runmin[4] = {FLT_MAX, FLT_MAX, FLT_MAX, FLT_MAX};

    for (int chunk = 0; chunk < VOCABN / 64; ++chunk) {
        const int c0 = chunk * 64;
        const short* bc = bp + (size_t)c0 * DIM;
        f32x4 acc[4];
        #pragma unroll
        for (int s = 0; s < 4; ++s) acc[s] = (f32x4){0.f, 0.f, 0.f, 0.f};

        #pragma unroll
        for (int kc = 0; kc < 24; ++kc) {
            const bf16x8 a = a_reg[kc];
            #pragma unroll
            for (int s = 0; s < 4; ++s) {
                const bf16x8 b = *(const bf16x8*)(bc + s * 16 * DIM + kc * 32);
                acc[s] = __builtin_amdgcn_mfma_f32_16x16x32_bf16(a, b, acc[s], 0, 0, 0);
            }
        }

        float d[4][4];
        float m[4] = {FLT_MAX, FLT_MAX, FLT_MAX, FLT_MAX};
        #pragma unroll
        for (int s = 0; s < 4; ++s) {
            const float csv = csq[c0 + s * 16 + lm];
            #pragma unroll
            for (int r = 0; r < 4; ++r) {
                d[s][r] = fmaf(-2.0f, acc[s][r], csv);
                m[r] = fminf(m[r], d[s][r]);
            }
        }
        #pragma unroll
        for (int r = 0; r < 4; ++r) {
            float vv = m[r];
            vv = fminf(vv, __shfl_xor(vv, 1));
            vv = fminf(vv, __shfl_xor(vv, 2));
            vv = fminf(vv, __shfl_xor(vv, 4));
            vv = fminf(vv, __shfl_xor(vv, 8));
            runmin[r] = fminf(runmin[r], vv);
        }
        #pragma unroll
        for (int s = 0; s < 4; ++s) {
            #pragma unroll
            for (int r = 0; r < 4; ++r) {
                if (d[s][r] <= runmin[r] + MARGIN) {
                    const int qloc = w * 16 + quad * 4 + r;
                    const int idx = atomicAdd(&s_cnt[qloc], 1);
                    if (idx < CAP) s_cand[qloc][idx] = c0 + s * 16 + lm;
                }
            }
        }
    }
    __syncthreads();

    const int qloc = t >> 2;
    const int sub = t & 3;
    const int qg = q0 + qloc;
    int n = s_cnt[qloc];
    if (n > CAP) n = CAP;
    float bestd = FLT_MAX;
    int bestc = 0x7fffffff;
    const float4* xr = (const float4*)(comb + (size_t)qg * DIM);
    for (int i = 0; i < n; ++i) {
        const int c = s_cand[qloc][i];
        const float4* cr = (const float4*)(codebook + (size_t)c * DIM);
        float dot = 0.0f;
        #pragma unroll 4
        for (int j = sub * 48; j < sub * 48 + 48; ++j) {
            const float4 x = xr[j];
            const float4 y = cr[j];
            dot = fmaf(x.x, y.x, fmaf(x.y, y.y, fmaf(x.z, y.z, fmaf(x.w, y.w, dot))));
        }
        dot += __shfl_xor(dot, 1);
        dot += __shfl_xor(dot, 2);
        const float dist = fmaf(-2.0f, dot, csq[c]);
        if (dist < bestd || (dist == bestd && c < bestc)) { bestd = dist; bestc = c; }
    }
    if (sub == 0) {
        out_tok_f[qg] = (float)bestc;
        tok_i[qg] = bestc;
    }
}

__global__ __launch_bounds__(192) void gather_kernel(
    const int* __restrict__ tok, const float* __restrict__ codebook,
    float* __restrict__ outq)
{
    const int row = blockIdx.x;
    const int t = threadIdx.x;
    const int token = tok[row];
    const float4* cb4 = (const float4*)(codebook + (size_t)token * DIM);
    float4* o4 = (float4*)(outq + (size_t)row * DIM);
    o4[t] = cb4[t];
}

// ===========================================================================
extern "C" void kernel_launch(void* const* d_in, const int* in_sizes, int n_in,
                              void* d_out, int out_size, void* d_ws, size_t ws_size,
                              hipStream_t stream) {
    const float* coords   = (const float*)d_in[0];
    const float* feats    = (const float*)d_in[1];
    const float* Ws1      = (const float*)d_in[2];
    const float* bs1      = (const float*)d_in[3];
    const float* Ws2      = (const float*)d_in[4];
    const float* bs2      = (const float*)d_in[5];
    const float* Wf1      = (const float*)d_in[6];
    const float* bf1      = (const float*)d_in[7];
    const float* Wf2      = (const float*)d_in[8];
    const float* bf2      = (const float*)d_in[9];
    const float* codebook = (const float*)d_in[10];

    float* out = (float*)d_out;            // [32768 tokens][25165824 quantized]
    float* out_tok = out;
    float* out_q   = out + M_ROWS;

    const size_t SZ_COMB32 = (size_t)M_ROWS * DIM * 4;          // 100.66 MB
    const size_t SZ_COMB16 = (size_t)M_ROWS * DIM * 2;          //  50.33 MB
    const size_t SZ_CBB    = (size_t)VOCABN * DIM * 2;          //   6.29 MB
    const size_t SZ_CSQ    = (size_t)VOCABN * 4;
    const size_t SZ_LMIN   = (size_t)M_ROWS * NCB2 * 4;         //   2 MB
    const size_t SZ_LCI    = (size_t)M_ROWS * NCB2 * CAP2 * 4;  //  12.6 MB
    const size_t NEED = SZ_COMB32 + SZ_COMB16 + SZ_CBB + SZ_CSQ +
                        3 * SZ_LMIN + SZ_LCI;                   // ~176 MB

    char* p = (char*)d_ws;
    float* comb32 = (float*)p;              p += SZ_COMB32;
    short* comb16f = (short*)p;             p += SZ_COMB16;   // fragment order
    short* cbx = (short*)p;                 p += SZ_CBB;      // frag (main) / row (fb)
    float* csq = (float*)p;                 p += SZ_CSQ;

    if (ws_size >= NEED) {
        float* lmin_g = (float*)p;          p += SZ_LMIN;
        int*   lbidx_g = (int*)p;           p += SZ_LMIN;
        int*   lcnt_g = (int*)p;            p += SZ_LMIN;
        int*   lci_g = (int*)p;             p += SZ_LCI;

        encode_kernel<<<M_ROWS / 32, 256, 0, stream>>>(
            coords, feats, Ws1, bs1, Ws2, bs2, Wf1, bf1, Wf2, bf2,
            comb32, comb16f, 1);
        csq_cvt_kernel<<<VOCABN, 64, 0, stream>>>(codebook, csq, cbx, 1);
        dim3 g1(NCB2, M_ROWS / BM2, 1);     // (16, 128)
        vq_phase1_kernel<<<g1, 512, 0, stream>>>(
            comb16f, cbx, csq, lmin_g, lbidx_g, lcnt_g, lci_g);
        vq_phase2_kernel<<<M_ROWS / 4, 256, 0, stream>>>(
            comb32, codebook, csq, lmin_g, lbidx_g, lcnt_g, lci_g,
            out_tok, out_q);
    } else {
        // R2 fallback: comb32 + cbb(row-major) + csq + toki
        int* toki = (int*)p;
        encode_kernel<<<M_ROWS / 32, 256, 0, stream>>>(
            coords, feats, Ws1, bs1, Ws2, bs2, Wf1, bf1, Wf2, bf2,
            comb32, comb16f, 0);
        csq_cvt_kernel<<<VOCABN, 64, 0, stream>>>(codebook, csq, cbx, 0);
        argmin_mfma_kernel<<<M_ROWS / QB, 256, 0, stream>>>(
            comb32, codebook, cbx, csq, out_tok, toki);
        gather_kernel<<<M_ROWS, 192, 0, stream>>>(toki, codebook, out_q);
    }
}

// Round 5
// 665.501 us; speedup vs baseline: 1.0742x; 1.0742x over previous
//
#include <hip/hip_runtime.h>
#include <hip/hip_bf16.h>
#include <cfloat>

// Problem constants (GeoTokenizer): B=8, N=4096 -> M=32768 rows
#define M_ROWS 32768
#define DIM    768
#define VOCABN 4096
#define HIDN   128
#define QB     64      // (fallback) queries per argmin block
#define CAP    32      // (fallback) candidate buffer per query
#define MARGIN 2.0f    // 2*delta; |approx-exact| bound delta=1.0 (validated R2-R4)

// Phase-1 GEMM tiling (m97-structure: 128x128 tile, 4 waves, 3 blocks/CU)
#define BM1 128
#define BN1 128
#define NCB (VOCABN / BN1)   // 32 code-blocks of 128
#define CAP2 6               // stored candidates per (query, code-block)
#define NKC  (DIM / 32)      // 24 k-chunks of 32

typedef __attribute__((ext_vector_type(8))) short bf16x8;  // MFMA A/B frag
typedef __attribute__((ext_vector_type(4))) float f32x4;   // MFMA C/D frag

static __device__ __forceinline__ short f2b(float x) {
    __hip_bfloat16 h = __float2bfloat16(x);   // RNE
    return *reinterpret_cast<short*>(&h);
}

// async global->LDS, 16B per lane; LDS dest is wave-uniform base + lane*16
static __device__ __forceinline__ void gload_lds16(const void* g, void* l) {
    __builtin_amdgcn_global_load_lds(
        (const __attribute__((address_space(1))) unsigned int*)g,
        (__attribute__((address_space(3))) unsigned int*)l, 16, 0, 0);
}

// Fragment-unit indexing (16 B units of 8 bf16), GLOBAL row-tile rt = row>>4:
//   A: unit = (rt*NKC + kc)*64 + lane
//      holds comb[row = rt*16 + (lane&15)][k = kc*32 + (lane>>4)*8 ..+8]
//   B: unit = (ct*NKC + kc)*64 + lane   (ct = code>>4)

// ---------------------------------------------------------------------------
// Kernel 1: fused two-branch MLP encoder (fp32 exact). 32 rows/block.
// write16: emits comb16 in A-FRAGMENT order (scattered shorts, L2-combined).
// ---------------------------------------------------------------------------
__global__ __launch_bounds__(256) void encode_kernel(
    const float* __restrict__ coords, const float* __restrict__ feats,
    const float* __restrict__ Ws1, const float* __restrict__ bs1,
    const float* __restrict__ Ws2, const float* __restrict__ bs2,
    const float* __restrict__ Wf1, const float* __restrict__ bf1,
    const float* __restrict__ Wf2, const float* __restrict__ bf2,
    float* __restrict__ comb, short* __restrict__ comb16f, int write16)
{
    __shared__ float hs[32][HIDN];
    __shared__ float hf[32][HIDN];
    const int row0 = blockIdx.x * 32;
    const int t = threadIdx.x;

    #pragma unroll
    for (int k = 0; k < 16; ++k) {
        const int idx = t + k * 256;
        const int r = idx >> 7;
        const int j = idx & 127;
        const int row = row0 + r;
        const float c0 = coords[row * 2 + 0];
        const float c1 = coords[row * 2 + 1];
        float vs = fmaf(c0, Ws1[j], fmaf(c1, Ws1[HIDN + j], bs1[j]));
        hs[r][j] = fmaxf(vs, 0.0f);
        float vf = bf1[j];
        #pragma unroll
        for (int i = 0; i < 10; ++i)
            vf = fmaf(feats[row * 10 + i], Wf1[i * HIDN + j], vf);
        hf[r][j] = fmaxf(vf, 0.0f);
    }
    __syncthreads();

    float acc[3][32];
    #pragma unroll
    for (int dd = 0; dd < 3; ++dd) {
        const float base = bs2[t + dd * 256] + bf2[t + dd * 256];
        #pragma unroll
        for (int r = 0; r < 32; ++r) acc[dd][r] = base;
    }

    for (int jq = 0; jq < 32; ++jq) {
        float ws[3][4], wf[3][4];
        #pragma unroll
        for (int dd = 0; dd < 3; ++dd) {
            const int d = t + dd * 256;
            #pragma unroll
            for (int jj = 0; jj < 4; ++jj) {
                ws[dd][jj] = Ws2[(jq * 4 + jj) * DIM + d];
                wf[dd][jj] = Wf2[(jq * 4 + jj) * DIM + d];
            }
        }
        #pragma unroll
        for (int r = 0; r < 32; ++r) {
            const float4 h4s = *(const float4*)&hs[r][jq * 4];
            const float4 h4f = *(const float4*)&hf[r][jq * 4];
            #pragma unroll
            for (int dd = 0; dd < 3; ++dd) {
                float a = acc[dd][r];
                a = fmaf(h4s.x, ws[dd][0], a);
                a = fmaf(h4s.y, ws[dd][1], a);
                a = fmaf(h4s.z, ws[dd][2], a);
                a = fmaf(h4s.w, ws[dd][3], a);
                a = fmaf(h4f.x, wf[dd][0], a);
                a = fmaf(h4f.y, wf[dd][1], a);
                a = fmaf(h4f.z, wf[dd][2], a);
                a = fmaf(h4f.w, wf[dd][3], a);
                acc[dd][r] = a;
            }
        }
    }

    const int qt = row0 >> 7;   // 128-row group (qt*8+it == row>>4, global rt)
    #pragma unroll
    for (int dd = 0; dd < 3; ++dd) {
        const int d = t + dd * 256;
        const int kc = d >> 5, kg = (d >> 3) & 3, jj = d & 7;
        #pragma unroll
        for (int r = 0; r < 32; ++r) {
            const int row = row0 + r;
            const float v = acc[dd][r];
            comb[(size_t)row * DIM + d] = v;
            if (write16) {
                const int it = (row >> 4) & 7, n = row & 15;
                const size_t unit = ((size_t)(qt * 8 + it) * NKC + kc) * 64 + kg * 16 + n;
                comb16f[unit * 8 + jj] = f2b(v);
            }
        }
    }
}

// ---------------------------------------------------------------------------
// Kernel 2: c_sq (fp32) + bf16 codebook conversion.
// swizzled=1 -> B-fragment order (main path); 0 -> row-major (fallback path).
// ---------------------------------------------------------------------------
__global__ __launch_bounds__(64) void csq_cvt_kernel(
    const float* __restrict__ codebook, float* __restrict__ csq,
    short* __restrict__ outb, int swizzled)
{
    const int v = blockIdx.x;
    const int l = threadIdx.x;
    float s = 0.0f;
    #pragma unroll
    for (int k = 0; k < DIM / 64; ++k) {
        const float x = codebook[(size_t)v * DIM + l + k * 64];
        if (!swizzled) outb[(size_t)v * DIM + l + k * 64] = f2b(x);
        s = fmaf(x, x, s);
    }
    #pragma unroll
    for (int off = 32; off >= 1; off >>= 1)
        s += __shfl_down(s, off);
    if (l == 0) csq[v] = s;

    if (swizzled) {
        const int cb = v >> 7, jt = (v >> 4) & 7, n = v & 15;
        for (int u = l; u < 96; u += 64) {      // 24 kc x 4 kg
            const int kc = u >> 2, kg = u & 3;
            const float* src = codebook + (size_t)v * DIM + kc * 32 + kg * 8;
            bf16x8 f;
            #pragma unroll
            for (int j = 0; j < 8; ++j) f[j] = f2b(src[j]);
            const size_t unit = ((size_t)(cb * 8 + jt) * NKC + kc) * 64 + kg * 16 + n;
            *(bf16x8*)(outb + unit * 8) = f;
        }
    }
}

// ---------------------------------------------------------------------------
// Kernel 3 (phase 1): m97-structure MFMA GEMM. R4's phase-split raced (post-
// timing tripwire; m152 lesson: new sync templates need race screens we can't
// run headlessly). R5 retreat: compiler-managed sync only.
//   Why 128^2: the 256^2 tile's 128-reg accumulator forces 2 waves/SIMD ->
//   1 block/CU -> every barrier drains the WHOLE CU (the measured 2-phase
//   plateau, ~650 TF). The 128^2 tile (64-reg acc, 32 KB LDS,
//   __launch_bounds__(256,3)) runs 3 blocks/CU: inter-block co-scheduling
//   hides the drain (m114 mechanism; m103: 912 TF refcheck'd with exactly
//   this structure -- plain __syncthreads, no inline asm).
//   - 4 waves (2x2), wave tile 64x64 (acc 4x4 f32x4 = 64 regs)
//   - BK=32, 2x16 KB LDS dbuf; stage(kc+1) issued first, one __syncthreads
//     per step (compiler emits vmcnt(0)+lgkm(0) drain before s_barrier ->
//     WAR/RAW safe by construction)
//   - operands pre-swizzled in fragment order -> linear LDS dest, no bank
//     conflicts
//   - XCD chunk map: 8192 blocks = 8 xcd x 16 rounds x 64 slots (4qt x 16cb);
//     cb-half fixed per XCD -> B working set 3 MB L2-resident (R3-proven
//     FETCH reduction). Bijective; per-block math identical -> distances
//     bitwise equal to R0's validated partition (NCB=32, CAP2=6).
// ---------------------------------------------------------------------------
__global__ __launch_bounds__(256, 3) void vq_phase1_kernel(
    const short* __restrict__ comb16f, const short* __restrict__ cbf,
    const float* __restrict__ csq,
    float* __restrict__ lmin_g, int* __restrict__ lbidx_g,
    int* __restrict__ lcnt_g, int* __restrict__ lci_g)
{
    __shared__ __align__(16) char smem[2 * 16384];   // 32 KB double buffer

    const int t = threadIdx.x;
    const int w = t >> 6, l = t & 63;
    const int lm = l & 15, quad = l >> 4;
    const int wr = w >> 1, wc = w & 1;           // 2 x 2 wave grid

    // XCD chunk mapping: lin = 8 xcd x 16 rounds x 64 slots (bijective)
    const int lin = blockIdx.y * (int)gridDim.x + blockIdx.x;
    const int x  = lin & 7;                      // XCD (round-robin assumption)
    const int s_ = (lin >> 3) & 63;              // slot within XCD window
    const int r_ = lin >> 9;                     // round 0..15
    const int qt = (r_ * 4 + (x >> 1)) * 4 + (s_ >> 4);   // 0..255
    const int cb = (x & 1) * 16 + (s_ & 15);              // 0..31
    const int q0 = qt * BM1;

    // staging: wave w owns frag-sets s = w*4..w*4+3 (s<8: A rt-set; else B)
    const short* gsrc[4];
    int doff[4];
    #pragma unroll
    for (int k = 0; k < 4; ++k) {
        const int s = w * 4 + k;
        if (s < 8) {
            gsrc[k] = comb16f + (((size_t)(qt * 8 + s) * NKC) * 64 + l) * 8;
            doff[k] = s * 1024;
        } else {
            gsrc[k] = cbf + (((size_t)(cb * 8 + (s - 8)) * NKC) * 64 + l) * 8;
            doff[k] = 8192 + (s - 8) * 1024;
        }
    }

    f32x4 acc[4][4];
    #pragma unroll
    for (int i = 0; i < 4; ++i)
        #pragma unroll
        for (int j = 0; j < 4; ++j) acc[i][j] = (f32x4){0.f, 0.f, 0.f, 0.f};

    // one STAGE = this wave's 4 frag-sets (4 KB) for K-step kc into buf kc&1
    #define STAGE(kc) do {                                                      \
        char* _d = smem + ((kc) & 1) * 16384;                                   \
        _Pragma("unroll")                                                       \
        for (int _k = 0; _k < 4; ++_k)                                          \
            gload_lds16(gsrc[_k] + (size_t)(kc) * 512, _d + doff[_k]);          \
    } while (0)

    STAGE(0);
    __syncthreads();                              // full drain incl. vmcnt(0)

    #pragma unroll
    for (int kc = 0; kc < NKC; ++kc) {
        if (kc + 1 < NKC) STAGE(kc + 1);          // prefetch next K-step
        const char* buf = smem + (kc & 1) * 16384;
        bf16x8 a[4], b[4];
        #pragma unroll
        for (int i = 0; i < 4; ++i)
            a[i] = *(const bf16x8*)(buf + (wr * 4 + i) * 1024 + l * 16);
        #pragma unroll
        for (int j = 0; j < 4; ++j)
            b[j] = *(const bf16x8*)(buf + 8192 + (wc * 4 + j) * 1024 + l * 16);
        #pragma unroll
        for (int i = 0; i < 4; ++i)
            #pragma unroll
            for (int j = 0; j < 4; ++j)
                acc[i][j] = __builtin_amdgcn_mfma_f32_16x16x32_bf16(
                    a[i], b[j], acc[i][j], 0, 0, 0);
        if (kc + 1 < NKC) __syncthreads();        // drains stage(kc+1) + reads
    }
    #undef STAGE

    // ---- epilogue (R0-proven logic at BM=128/NCB=32; reuses LDS) ----
    float* s_wmin = (float*)smem;               // [2][128]  1 KB
    int*   s_widx = (int*)(smem + 1024);        // [2][128]  1 KB
    float* s_thr  = (float*)(smem + 2048);      // [128]     0.5 KB
    int*   s_cnt  = (int*)(smem + 2560);        // [128]     0.5 KB
    int*   s_ci   = (int*)(smem + 3072);        // [128][CAP2] 3 KB

    __syncthreads();
    if (t < BM1) s_cnt[t] = 0;

    const int cbase = cb * BN1 + wc * 64;
    float cs[4];
    #pragma unroll
    for (int j = 0; j < 4; ++j) cs[j] = csq[cbase + j * 16 + lm];
    #pragma unroll
    for (int i = 0; i < 4; ++i)
        #pragma unroll
        for (int j = 0; j < 4; ++j)
            #pragma unroll
            for (int r = 0; r < 4; ++r)
                acc[i][j][r] = fmaf(-2.0f, acc[i][j][r], cs[j]);

    // per-query (i,r) min/argmin over j-tiles then over 16 lanes of the quad
    #pragma unroll
    for (int i = 0; i < 4; ++i)
        #pragma unroll
        for (int r = 0; r < 4; ++r) {
            float m = acc[i][0][r];
            int mi = cbase + 0 * 16 + lm;
            #pragma unroll
            for (int j = 1; j < 4; ++j) {
                const float d = acc[i][j][r];
                const int ci = cbase + j * 16 + lm;
                if (d < m || (d == m && ci < mi)) { m = d; mi = ci; }
            }
            #pragma unroll
            for (int off = 1; off <= 8; off <<= 1) {   // stays within quad
                const float om = __shfl_xor(m, off);
                const int oi = __shfl_xor(mi, off);
                if (om < m || (om == m && oi < mi)) { m = om; mi = oi; }
            }
            if (lm == 0) {
                const int qloc = wr * 64 + i * 16 + quad * 4 + r;
                s_wmin[wc * 128 + qloc] = m;
                s_widx[wc * 128 + qloc] = mi;
            }
        }
    __syncthreads();

    if (t < BM1) {
        const float v0 = s_wmin[t], v1 = s_wmin[128 + t];
        const int i0 = s_widx[t], i1 = s_widx[128 + t];
        const float bm = fminf(v0, v1);
        const int bi = (v1 < v0 || (v1 == v0 && i1 < i0)) ? i1 : i0;
        const size_t base = (size_t)cb * M_ROWS + (q0 + t);   // [cb][q] coalesced
        lmin_g[base] = bm;
        lbidx_g[base] = bi;
        s_thr[t] = bm + MARGIN;
    }
    __syncthreads();

    // candidate pass: push everything within margin of the block-local min
    #pragma unroll
    for (int i = 0; i < 4; ++i)
        #pragma unroll
        for (int r = 0; r < 4; ++r) {
            const int qloc = wr * 64 + i * 16 + quad * 4 + r;
            const float thr = s_thr[qloc];
            #pragma unroll
            for (int j = 0; j < 4; ++j) {
                const float d = acc[i][j][r];
                if (d <= thr) {
                    const int p = atomicAdd(&s_cnt[qloc], 1);
                    if (p < CAP2) s_ci[qloc * CAP2 + p] = cbase + j * 16 + lm;
                }
            }
        }
    __syncthreads();

    if (t < BM1) {
        const size_t base = (size_t)cb * M_ROWS + (q0 + t);
        int n = s_cnt[t];
        if (n > CAP2) n = CAP2;
        lcnt_g[base] = n;
        for (int p = 0; p < n; ++p)
            lci_g[base * CAP2 + p] = s_ci[t * CAP2 + p];
    }
}

// ---------------------------------------------------------------------------
// Kernel 4 (phase 2): G = min of 32 local mins; select cbs with lmin<=G+MARGIN
// (provable superset); exact fp32 re-rank of their anchors+candidates; fused
// gather. One wave per query; 4 queries per block. (R0-proven at NCB=32.)
// ---------------------------------------------------------------------------
#define P2CAP 48
__global__ __launch_bounds__(256) void vq_phase2_kernel(
    const float* __restrict__ comb32, const float* __restrict__ codebook,
    const float* __restrict__ csq,
    const float* __restrict__ lmin_g, const int* __restrict__ lbidx_g,
    const int* __restrict__ lcnt_g, const int* __restrict__ lci_g,
    float* __restrict__ out_tok_f, float* __restrict__ out_q)
{
    __shared__ int s2n[4];
    __shared__ int s2c[4][P2CAP];
    const int t = threadIdx.x, w = t >> 6, l = t & 63;
    const int q = blockIdx.x * 4 + w;
    if (l == 0) s2n[w] = 0;                 // wave-local; LDS ops in-order

    const size_t base = (size_t)l * M_ROWS + q;   // lane l = code-block l
    const float v = (l < NCB) ? lmin_g[base] : FLT_MAX;
    float g = v;
    #pragma unroll
    for (int off = 1; off <= 32; off <<= 1)
        g = fminf(g, __shfl_xor(g, off));
    const float thr = g + MARGIN;

    if (l < NCB && v <= thr) {
        int p = atomicAdd(&s2n[w], 1);
        if (p < P2CAP) s2c[w][p] = lbidx_g[base];   // anchor (cb-local argmin)
        int n = lcnt_g[base];
        if (n > CAP2) n = CAP2;
        for (int e = 0; e < n; ++e) {
            p = atomicAdd(&s2n[w], 1);
            if (p < P2CAP) s2c[w][p] = lci_g[base * CAP2 + e];
        }
    }
    __syncthreads();

    int ns = s2n[w];
    if (ns > P2CAP) ns = P2CAP;
    float bestd = FLT_MAX;
    int bestc = 0x7fffffff;
    const float4* xr = (const float4*)(comb32 + (size_t)q * DIM);
    for (int e = 0; e < ns; ++e) {
        const int c = s2c[w][e];
        const float4* cr = (const float4*)(codebook + (size_t)c * DIM);
        float dot = 0.0f;
        #pragma unroll
        for (int k = 0; k < 3; ++k) {
            const float4 x = xr[l + 64 * k];
            const float4 y = cr[l + 64 * k];
            dot = fmaf(x.x, y.x, fmaf(x.y, y.y, fmaf(x.z, y.z, fmaf(x.w, y.w, dot))));
        }
        #pragma unroll
        for (int off = 1; off <= 32; off <<= 1)
            dot += __shfl_xor(dot, off);     // bitwise-identical in all lanes
        const float d = fmaf(-2.0f, dot, csq[c]);
        if (d < bestd || (d == bestd && c < bestc)) { bestd = d; bestc = c; }
    }
    if (l == 0) out_tok_f[q] = (float)bestc;
    const float4* cr = (const float4*)(codebook + (size_t)bestc * DIM);
    float4* o4 = (float4*)(out_q + (size_t)q * DIM);
    #pragma unroll
    for (int k = 0; k < 3; ++k) o4[l + 64 * k] = cr[l + 64 * k];
}

// ===========================================================================
// FALLBACK PATH (R2, proven): used only if ws_size is too small.
// ===========================================================================
__global__ __launch_bounds__(256) void argmin_mfma_kernel(
    const float* __restrict__ comb, const float* __restrict__ codebook,
    const short* __restrict__ cbb, const float* __restrict__ csq,
    float* __restrict__ out_tok_f, int* __restrict__ tok_i)
{
    __shared__ int s_cnt[QB];
    __shared__ int s_cand[QB][CAP];

    const int t = threadIdx.x;
    const int w = t >> 6;
    const int l = t & 63;
    const int lm = l & 15;
    const int quad = l >> 4;
    const int q0 = blockIdx.x * QB;

    for (int i = t; i < QB; i += 256) s_cnt[i] = 0;
    __syncthreads();

    bf16x8 a_reg[24];
    {
        const int qa = q0 + w * 16 + lm;
        const float* ap = comb + (size_t)qa * DIM + quad * 8;
        #pragma unroll
        for (int kc = 0; kc < 24; ++kc) {
            const float4 lo = *(const float4*)(ap + kc * 32);
            const float4 hi = *(const float4*)(ap + kc * 32 + 4);
            bf16x8 f;
            f[0] = f2b(lo.x); f[1] = f2b(lo.y); f[2] = f2b(lo.z); f[3] = f2b(lo.w);
            f[4] = f2b(hi.x); f[5] = f2b(hi.y); f[6] = f2b(hi.z); f[7] = f2b(hi.w);
            a_reg[kc] = f;
        }
    }

    const short* bp = cbb + (size_t)lm * DIM + quad * 8;
    float runmin[4] = {FLT_MAX, FLT_MAX, FLT_MAX, FLT_MAX};

    for (int chunk = 0; chunk < VOCABN / 64; ++chunk) {
        const int c0 = chunk * 64;
        const short* bc = bp + (size_t)c0 * DIM;
        f32x4 acc[4];
        #pragma unroll
        for (int s = 0; s < 4; ++s) acc[s] = (f32x4){0.f, 0.f, 0.f, 0.f};

        #pragma unroll
        for (int kc = 0; kc < 24; ++kc) {
            const bf16x8 a = a_reg[kc];
            #pragma unroll
            for (int s = 0; s < 4; ++s) {
                const bf16x8 b = *(const bf16x8*)(bc + s * 16 * DIM + kc * 32);
                acc[s] = __builtin_amdgcn_mfma_f32_16x16x32_bf16(a, b, acc[s], 0, 0, 0);
            }
        }

        float d[4][4];
        float m[4] = {FLT_MAX, FLT_MAX, FLT_MAX, FLT_MAX};
        #pragma unroll
        for (int s = 0; s < 4; ++s) {
            const float csv = csq[c0 + s * 16 + lm];
            #pragma unroll
            for (int r = 0; r < 4; ++r) {
                d[s][r] = fmaf(-2.0f, acc[s][r], csv);
                m[r] = fminf(m[r], d[s][r]);
            }
        }
        #pragma unroll
        for (int r = 0; r < 4; ++r) {
            float vv = m[r];
            vv = fminf(vv, __shfl_xor(vv, 1));
            vv = fminf(vv, __shfl_xor(vv, 2));
            vv = fminf(vv, __shfl_xor(vv, 4));
            vv = fminf(vv, __shfl_xor(vv, 8));
            runmin[r] = fminf(runmin[r], vv);
        }
        #pragma unroll
        for (int s = 0; s < 4; ++s) {
            #pragma unroll
            for (int r = 0; r < 4; ++r) {
                if (d[s][r] <= runmin[r] + MARGIN) {
                    const int qloc = w * 16 + quad * 4 + r;
                    const int idx = atomicAdd(&s_cnt[qloc], 1);
                    if (idx < CAP) s_cand[qloc][idx] = c0 + s * 16 + lm;
                }
            }
        }
    }
    __syncthreads();

    const int qloc = t >> 2;
    const int sub = t & 3;
    const int qg = q0 + qloc;
    int n = s_cnt[qloc];
    if (n > CAP) n = CAP;
    float bestd = FLT_MAX;
    int bestc = 0x7fffffff;
    const float4* xr = (const float4*)(comb + (size_t)qg * DIM);
    for (int i = 0; i < n; ++i) {
        const int c = s_cand[qloc][i];
        const float4* cr = (const float4*)(codebook + (size_t)c * DIM);
        float dot = 0.0f;
        #pragma unroll 4
        for (int j = sub * 48; j < sub * 48 + 48; ++j) {
            const float4 x = xr[j];
            const float4 y = cr[j];
            dot = fmaf(x.x, y.x, fmaf(x.y, y.y, fmaf(x.z, y.z, fmaf(x.w, y.w, dot))));
        }
        dot += __shfl_xor(dot, 1);
        dot += __shfl_xor(dot, 2);
        const float dist = fmaf(-2.0f, dot, csq[c]);
        if (dist < bestd || (dist == bestd && c < bestc)) { bestd = dist; bestc = c; }
    }
    if (sub == 0) {
        out_tok_f[qg] = (float)bestc;
        tok_i[qg] = bestc;
    }
}

__global__ __launch_bounds__(192) void gather_kernel(
    const int* __restrict__ tok, const float* __restrict__ codebook,
    float* __restrict__ outq)
{
    const int row = blockIdx.x;
    const int t = threadIdx.x;
    const int token = tok[row];
    const float4* cb4 = (const float4*)(codebook + (size_t)token * DIM);
    float4* o4 = (float4*)(outq + (size_t)row * DIM);
    o4[t] = cb4[t];
}

// ===========================================================================
extern "C" void kernel_launch(void* const* d_in, const int* in_sizes, int n_in,
                              void* d_out, int out_size, void* d_ws, size_t ws_size,
                              hipStream_t stream) {
    const float* coords   = (const float*)d_in[0];
    const float* feats    = (const float*)d_in[1];
    const float* Ws1      = (const float*)d_in[2];
    const float* bs1      = (const float*)d_in[3];
    const float* Ws2      = (const float*)d_in[4];
    const float* bs2      = (const float*)d_in[5];
    const float* Wf1      = (const float*)d_in[6];
    const float* bf1      = (const float*)d_in[7];
    const float* Wf2      = (const float*)d_in[8];
    const float* bf2      = (const float*)d_in[9];
    const float* codebook = (const float*)d_in[10];

    float* out = (float*)d_out;            // [32768 tokens][25165824 quantized]
    float* out_tok = out;
    float* out_q   = out + M_ROWS;

    const size_t SZ_COMB32 = (size_t)M_ROWS * DIM * 4;          // 100.66 MB
    const size_t SZ_COMB16 = (size_t)M_ROWS * DIM * 2;          //  50.33 MB
    const size_t SZ_CBB    = (size_t)VOCABN * DIM * 2;          //   6.29 MB
    const size_t SZ_CSQ    = (size_t)VOCABN * 4;
    const size_t SZ_LMIN   = (size_t)M_ROWS * NCB * 4;          //   4 MB
    const size_t SZ_LCI    = (size_t)M_ROWS * NCB * CAP2 * 4;   //  25 MB
    const size_t NEED = SZ_COMB32 + SZ_COMB16 + SZ_CBB + SZ_CSQ +
                        3 * SZ_LMIN + SZ_LCI;                   // ~198 MB

    char* p = (char*)d_ws;
    float* comb32 = (float*)p;              p += SZ_COMB32;
    short* comb16f = (short*)p;             p += SZ_COMB16;   // fragment order
    short* cbx = (short*)p;                 p += SZ_CBB;      // frag (main) / row (fb)
    float* csq = (float*)p;                 p += SZ_CSQ;

    if (ws_size >= NEED) {
        float* lmin_g = (float*)p;          p += SZ_LMIN;
        int*   lbidx_g = (int*)p;           p += SZ_LMIN;
        int*   lcnt_g = (int*)p;            p += SZ_LMIN;
        int*   lci_g = (int*)p;             p += SZ_LCI;

        encode_kernel<<<M_ROWS / 32, 256, 0, stream>>>(
            coords, feats, Ws1, bs1, Ws2, bs2, Wf1, bf1, Wf2, bf2,
            comb32, comb16f, 1);
        csq_cvt_kernel<<<VOCABN, 64, 0, stream>>>(codebook, csq, cbx, 1);
        dim3 g1(NCB, M_ROWS / BM1, 1);      // (32, 256)
        vq_phase1_kernel<<<g1, 256, 0, stream>>>(
            comb16f, cbx, csq, lmin_g, lbidx_g, lcnt_g, lci_g);
        vq_phase2_kernel<<<M_ROWS / 4, 256, 0, stream>>>(
            comb32, codebook, csq, lmin_g, lbidx_g, lcnt_g, lci_g,
            out_tok, out_q);
    } else {
        // R2 fallback: comb32 + cbb(row-major) + csq + toki
        int* toki = (int*)p;
        encode_kernel<<<M_ROWS / 32, 256, 0, stream>>>(
            coords, feats, Ws1, bs1, Ws2, bs2, Wf1, bf1, Wf2, bf2,
            comb32, comb16f, 0);
        csq_cvt_kernel<<<VOCABN, 64, 0, stream>>>(codebook, csq, cbx, 0);
        argmin_mfma_kernel<<<M_ROWS / QB, 256, 0, stream>>>(
            comb32, codebook, cbx, csq, out_tok, toki);
        gather_kernel<<<M_ROWS, 192, 0, stream>>>(toki, codebook, out_q);
    }
}

// Round 6
// 616.532 us; speedup vs baseline: 1.1595x; 1.0794x over previous
//
#include <hip/hip_runtime.h>
#include <hip/hip_bf16.h>
#include <cfloat>

// Problem constants (GeoTokenizer): B=8, N=4096 -> M=32768 rows
#define M_ROWS 32768
#define DIM    768
#define VOCABN 4096
#define HIDN   128
#define QB     64      // (fallback) queries per argmin block
#define CAP    32      // (fallback) candidate buffer per query
#define MARGIN 2.0f    // 2*delta; |approx-exact| bound delta=1.0 (validated R2-R4)

// Phase-1 GEMM tiling (m97-structure: 128x128 tile, 4 waves, 3+ blocks/CU)
#define BM1 128
#define BN1 128
#define NCB (VOCABN / BN1)   // 32 code-blocks of 128
#define CAP2 6               // stored candidates per (query, code-block)
#define NKC  (DIM / 32)      // 24 k-chunks of 32

typedef __attribute__((ext_vector_type(8))) short bf16x8;  // MFMA A/B frag
typedef __attribute__((ext_vector_type(4))) float f32x4;   // MFMA C/D frag

static __device__ __forceinline__ short f2b(float x) {
    __hip_bfloat16 h = __float2bfloat16(x);   // RNE
    return *reinterpret_cast<short*>(&h);
}

// async global->LDS, 16B per lane; LDS dest is wave-uniform base + lane*16
static __device__ __forceinline__ void gload_lds16(const void* g, void* l) {
    __builtin_amdgcn_global_load_lds(
        (const __attribute__((address_space(1))) unsigned int*)g,
        (__attribute__((address_space(3))) unsigned int*)l, 16, 0, 0);
}

// Fragment-unit indexing (16 B units of 8 bf16), GLOBAL row-tile rt = row>>4:
//   A: unit = (rt*NKC + kc)*64 + lane
//      holds comb[row = rt*16 + (lane&15)][k = kc*32 + (lane>>4)*8 ..+8]
//   B: unit = (ct*NKC + kc)*64 + lane   (ct = code>>4)

// ---------------------------------------------------------------------------
// Kernel 1: fused two-branch MLP encoder (fp32 exact). 32 rows/block.
// write16: emits comb16 in A-FRAGMENT order (scattered shorts, L2-combined).
// ---------------------------------------------------------------------------
__global__ __launch_bounds__(256) void encode_kernel(
    const float* __restrict__ coords, const float* __restrict__ feats,
    const float* __restrict__ Ws1, const float* __restrict__ bs1,
    const float* __restrict__ Ws2, const float* __restrict__ bs2,
    const float* __restrict__ Wf1, const float* __restrict__ bf1,
    const float* __restrict__ Wf2, const float* __restrict__ bf2,
    float* __restrict__ comb, short* __restrict__ comb16f, int write16)
{
    __shared__ float hs[32][HIDN];
    __shared__ float hf[32][HIDN];
    const int row0 = blockIdx.x * 32;
    const int t = threadIdx.x;

    #pragma unroll
    for (int k = 0; k < 16; ++k) {
        const int idx = t + k * 256;
        const int r = idx >> 7;
        const int j = idx & 127;
        const int row = row0 + r;
        const float c0 = coords[row * 2 + 0];
        const float c1 = coords[row * 2 + 1];
        float vs = fmaf(c0, Ws1[j], fmaf(c1, Ws1[HIDN + j], bs1[j]));
        hs[r][j] = fmaxf(vs, 0.0f);
        float vf = bf1[j];
        #pragma unroll
        for (int i = 0; i < 10; ++i)
            vf = fmaf(feats[row * 10 + i], Wf1[i * HIDN + j], vf);
        hf[r][j] = fmaxf(vf, 0.0f);
    }
    __syncthreads();

    float acc[3][32];
    #pragma unroll
    for (int dd = 0; dd < 3; ++dd) {
        const float base = bs2[t + dd * 256] + bf2[t + dd * 256];
        #pragma unroll
        for (int r = 0; r < 32; ++r) acc[dd][r] = base;
    }

    for (int jq = 0; jq < 32; ++jq) {
        float ws[3][4], wf[3][4];
        #pragma unroll
        for (int dd = 0; dd < 3; ++dd) {
            const int d = t + dd * 256;
            #pragma unroll
            for (int jj = 0; jj < 4; ++jj) {
                ws[dd][jj] = Ws2[(jq * 4 + jj) * DIM + d];
                wf[dd][jj] = Wf2[(jq * 4 + jj) * DIM + d];
            }
        }
        #pragma unroll
        for (int r = 0; r < 32; ++r) {
            const float4 h4s = *(const float4*)&hs[r][jq * 4];
            const float4 h4f = *(const float4*)&hf[r][jq * 4];
            #pragma unroll
            for (int dd = 0; dd < 3; ++dd) {
                float a = acc[dd][r];
                a = fmaf(h4s.x, ws[dd][0], a);
                a = fmaf(h4s.y, ws[dd][1], a);
                a = fmaf(h4s.z, ws[dd][2], a);
                a = fmaf(h4s.w, ws[dd][3], a);
                a = fmaf(h4f.x, wf[dd][0], a);
                a = fmaf(h4f.y, wf[dd][1], a);
                a = fmaf(h4f.z, wf[dd][2], a);
                a = fmaf(h4f.w, wf[dd][3], a);
                acc[dd][r] = a;
            }
        }
    }

    const int qt = row0 >> 7;   // 128-row group (qt*8+it == row>>4, global rt)
    #pragma unroll
    for (int dd = 0; dd < 3; ++dd) {
        const int d = t + dd * 256;
        const int kc = d >> 5, kg = (d >> 3) & 3, jj = d & 7;
        #pragma unroll
        for (int r = 0; r < 32; ++r) {
            const int row = row0 + r;
            const float v = acc[dd][r];
            comb[(size_t)row * DIM + d] = v;
            if (write16) {
                const int it = (row >> 4) & 7, n = row & 15;
                const size_t unit = ((size_t)(qt * 8 + it) * NKC + kc) * 64 + kg * 16 + n;
                comb16f[unit * 8 + jj] = f2b(v);
            }
        }
    }
}

// ---------------------------------------------------------------------------
// Kernel 2: c_sq (fp32) + bf16 codebook conversion.
// swizzled=1 -> B-fragment order (main path); 0 -> row-major (fallback path).
// ---------------------------------------------------------------------------
__global__ __launch_bounds__(64) void csq_cvt_kernel(
    const float* __restrict__ codebook, float* __restrict__ csq,
    short* __restrict__ outb, int swizzled)
{
    const int v = blockIdx.x;
    const int l = threadIdx.x;
    float s = 0.0f;
    #pragma unroll
    for (int k = 0; k < DIM / 64; ++k) {
        const float x = codebook[(size_t)v * DIM + l + k * 64];
        if (!swizzled) outb[(size_t)v * DIM + l + k * 64] = f2b(x);
        s = fmaf(x, x, s);
    }
    #pragma unroll
    for (int off = 32; off >= 1; off >>= 1)
        s += __shfl_down(s, off);
    if (l == 0) csq[v] = s;

    if (swizzled) {
        const int cb = v >> 7, jt = (v >> 4) & 7, n = v & 15;
        for (int u = l; u < 96; u += 64) {      // 24 kc x 4 kg
            const int kc = u >> 2, kg = u & 3;
            const float* src = codebook + (size_t)v * DIM + kc * 32 + kg * 8;
            bf16x8 f;
            #pragma unroll
            for (int j = 0; j < 8; ++j) f[j] = f2b(src[j]);
            const size_t unit = ((size_t)(cb * 8 + jt) * NKC + kc) * 64 + kg * 16 + n;
            *(bf16x8*)(outb + unit * 8) = f;
        }
    }
}

// ---------------------------------------------------------------------------
// Kernel 3 (phase 1): m97-structure MFMA GEMM (R5-validated, 297us).
// 128^2 tile, 4 waves (2x2), BK=32, 2x16KB LDS dbuf, one __syncthreads per
// K-step (compiler-managed drain -> race-free), operands pre-swizzled ->
// linear LDS dest. XCD chunk map (R3-proven FETCH reduction).
// R6 delta: lcnt_g now stores the RAW candidate count (list still capped at
// CAP2) so phase2 can skip the duplicate anchor dot when the list wasn't
// capped (the anchor provably sits in the list in that case).
// ---------------------------------------------------------------------------
__global__ __launch_bounds__(256, 3) void vq_phase1_kernel(
    const short* __restrict__ comb16f, const short* __restrict__ cbf,
    const float* __restrict__ csq,
    float* __restrict__ lmin_g, int* __restrict__ lbidx_g,
    int* __restrict__ lcnt_g, int* __restrict__ lci_g)
{
    __shared__ __align__(16) char smem[2 * 16384];   // 32 KB double buffer

    const int t = threadIdx.x;
    const int w = t >> 6, l = t & 63;
    const int lm = l & 15, quad = l >> 4;
    const int wr = w >> 1, wc = w & 1;           // 2 x 2 wave grid

    // XCD chunk mapping: lin = 8 xcd x 16 rounds x 64 slots (bijective)
    const int lin = blockIdx.y * (int)gridDim.x + blockIdx.x;
    const int x  = lin & 7;                      // XCD (round-robin assumption)
    const int s_ = (lin >> 3) & 63;              // slot within XCD window
    const int r_ = lin >> 9;                     // round 0..15
    const int qt = (r_ * 4 + (x >> 1)) * 4 + (s_ >> 4);   // 0..255
    const int cb = (x & 1) * 16 + (s_ & 15);              // 0..31
    const int q0 = qt * BM1;

    // staging: wave w owns frag-sets s = w*4..w*4+3 (s<8: A rt-set; else B)
    const short* gsrc[4];
    int doff[4];
    #pragma unroll
    for (int k = 0; k < 4; ++k) {
        const int s = w * 4 + k;
        if (s < 8) {
            gsrc[k] = comb16f + (((size_t)(qt * 8 + s) * NKC) * 64 + l) * 8;
            doff[k] = s * 1024;
        } else {
            gsrc[k] = cbf + (((size_t)(cb * 8 + (s - 8)) * NKC) * 64 + l) * 8;
            doff[k] = 8192 + (s - 8) * 1024;
        }
    }

    f32x4 acc[4][4];
    #pragma unroll
    for (int i = 0; i < 4; ++i)
        #pragma unroll
        for (int j = 0; j < 4; ++j) acc[i][j] = (f32x4){0.f, 0.f, 0.f, 0.f};

    // one STAGE = this wave's 4 frag-sets (4 KB) for K-step kc into buf kc&1
    #define STAGE(kc) do {                                                      \
        char* _d = smem + ((kc) & 1) * 16384;                                   \
        _Pragma("unroll")                                                       \
        for (int _k = 0; _k < 4; ++_k)                                          \
            gload_lds16(gsrc[_k] + (size_t)(kc) * 512, _d + doff[_k]);          \
    } while (0)

    STAGE(0);
    __syncthreads();                              // full drain incl. vmcnt(0)

    #pragma unroll
    for (int kc = 0; kc < NKC; ++kc) {
        if (kc + 1 < NKC) STAGE(kc + 1);          // prefetch next K-step
        const char* buf = smem + (kc & 1) * 16384;
        bf16x8 a[4], b[4];
        #pragma unroll
        for (int i = 0; i < 4; ++i)
            a[i] = *(const bf16x8*)(buf + (wr * 4 + i) * 1024 + l * 16);
        #pragma unroll
        for (int j = 0; j < 4; ++j)
            b[j] = *(const bf16x8*)(buf + 8192 + (wc * 4 + j) * 1024 + l * 16);
        #pragma unroll
        for (int i = 0; i < 4; ++i)
            #pragma unroll
            for (int j = 0; j < 4; ++j)
                acc[i][j] = __builtin_amdgcn_mfma_f32_16x16x32_bf16(
                    a[i], b[j], acc[i][j], 0, 0, 0);
        if (kc + 1 < NKC) __syncthreads();        // drains stage(kc+1) + reads
    }
    #undef STAGE

    // ---- epilogue (R0-proven logic at BM=128/NCB=32; reuses LDS) ----
    float* s_wmin = (float*)smem;               // [2][128]  1 KB
    int*   s_widx = (int*)(smem + 1024);        // [2][128]  1 KB
    float* s_thr  = (float*)(smem + 2048);      // [128]     0.5 KB
    int*   s_cnt  = (int*)(smem + 2560);        // [128]     0.5 KB
    int*   s_ci   = (int*)(smem + 3072);        // [128][CAP2] 3 KB

    __syncthreads();
    if (t < BM1) s_cnt[t] = 0;

    const int cbase = cb * BN1 + wc * 64;
    float cs[4];
    #pragma unroll
    for (int j = 0; j < 4; ++j) cs[j] = csq[cbase + j * 16 + lm];
    #pragma unroll
    for (int i = 0; i < 4; ++i)
        #pragma unroll
        for (int j = 0; j < 4; ++j)
            #pragma unroll
            for (int r = 0; r < 4; ++r)
                acc[i][j][r] = fmaf(-2.0f, acc[i][j][r], cs[j]);

    // per-query (i,r) min/argmin over j-tiles then over 16 lanes of the quad
    #pragma unroll
    for (int i = 0; i < 4; ++i)
        #pragma unroll
        for (int r = 0; r < 4; ++r) {
            float m = acc[i][0][r];
            int mi = cbase + 0 * 16 + lm;
            #pragma unroll
            for (int j = 1; j < 4; ++j) {
                const float d = acc[i][j][r];
                const int ci = cbase + j * 16 + lm;
                if (d < m || (d == m && ci < mi)) { m = d; mi = ci; }
            }
            #pragma unroll
            for (int off = 1; off <= 8; off <<= 1) {   // stays within quad
                const float om = __shfl_xor(m, off);
                const int oi = __shfl_xor(mi, off);
                if (om < m || (om == m && oi < mi)) { m = om; mi = oi; }
            }
            if (lm == 0) {
                const int qloc = wr * 64 + i * 16 + quad * 4 + r;
                s_wmin[wc * 128 + qloc] = m;
                s_widx[wc * 128 + qloc] = mi;
            }
        }
    __syncthreads();

    if (t < BM1) {
        const float v0 = s_wmin[t], v1 = s_wmin[128 + t];
        const int i0 = s_widx[t], i1 = s_widx[128 + t];
        const float bm = fminf(v0, v1);
        const int bi = (v1 < v0 || (v1 == v0 && i1 < i0)) ? i1 : i0;
        const size_t base = (size_t)cb * M_ROWS + (q0 + t);   // [cb][q] coalesced
        lmin_g[base] = bm;
        lbidx_g[base] = bi;
        s_thr[t] = bm + MARGIN;
    }
    __syncthreads();

    // candidate pass: push everything within margin of the block-local min
    #pragma unroll
    for (int i = 0; i < 4; ++i)
        #pragma unroll
        for (int r = 0; r < 4; ++r) {
            const int qloc = wr * 64 + i * 16 + quad * 4 + r;
            const float thr = s_thr[qloc];
            #pragma unroll
            for (int j = 0; j < 4; ++j) {
                const float d = acc[i][j][r];
                if (d <= thr) {
                    const int p = atomicAdd(&s_cnt[qloc], 1);
                    if (p < CAP2) s_ci[qloc * CAP2 + p] = cbase + j * 16 + lm;
                }
            }
        }
    __syncthreads();

    if (t < BM1) {
        const size_t base = (size_t)cb * M_ROWS + (q0 + t);
        const int raw = s_cnt[t];
        lcnt_g[base] = raw;                  // RAW count (R6: dedupe signal)
        int n = raw;
        if (n > CAP2) n = CAP2;
        for (int p = 0; p < n; ++p)
            lci_g[base * CAP2 + p] = s_ci[t * CAP2 + p];
    }
}

// ---------------------------------------------------------------------------
// Kernel 4 (phase 2): G = min of 32 local mins; select cbs with lmin<=G+MARGIN
// (provable superset); exact fp32 re-rank; fused gather.
// R6: (a) anchor pushed ONLY if the cb's candidate list was capped (raw>CAP2)
//     -- otherwise the anchor (d=bm<=bm+MARGIN) is provably IN the list, so
//     the re-ranked SET is identical minus duplicates (~1 dup per selected cb
//     eliminated, typically 30-45% of the dots);
// (b) query row cached in 12 regs (read once, not per candidate);
// (c) 2-way candidate ILP: two codebook rows in flight to hide the random-
//     gather L2/L3 latency (~400-600 cyc) under the dot+reduce of the pair.
// Result-identical: same distance formula, same tie-break (commutative).
// ---------------------------------------------------------------------------
#define P2CAP 48
__global__ __launch_bounds__(256) void vq_phase2_kernel(
    const float* __restrict__ comb32, const float* __restrict__ codebook,
    const float* __restrict__ csq,
    const float* __restrict__ lmin_g, const int* __restrict__ lbidx_g,
    const int* __restrict__ lcnt_g, const int* __restrict__ lci_g,
    float* __restrict__ out_tok_f, float* __restrict__ out_q)
{
    __shared__ int s2n[4];
    __shared__ int s2c[4][P2CAP];
    const int t = threadIdx.x, w = t >> 6, l = t & 63;
    const int q = blockIdx.x * 4 + w;
    if (l == 0) s2n[w] = 0;                 // wave-local; LDS ops in-order

    const size_t base = (size_t)l * M_ROWS + q;   // lane l = code-block l
    const float v = (l < NCB) ? lmin_g[base] : FLT_MAX;
    float g = v;
    #pragma unroll
    for (int off = 1; off <= 32; off <<= 1)
        g = fminf(g, __shfl_xor(g, off));
    const float thr = g + MARGIN;

    if (l < NCB && v <= thr) {
        const int raw = lcnt_g[base];
        int n = raw;
        if (n > CAP2) n = CAP2;
        if (raw > CAP2) {                   // anchor may have been dropped
            const int p = atomicAdd(&s2n[w], 1);
            if (p < P2CAP) s2c[w][p] = lbidx_g[base];
        }
        for (int e = 0; e < n; ++e) {
            const int p = atomicAdd(&s2n[w], 1);
            if (p < P2CAP) s2c[w][p] = lci_g[base * CAP2 + e];
        }
    }
    __syncthreads();

    int ns = s2n[w];
    if (ns > P2CAP) ns = P2CAP;

    // cache the query row: 12 float4 in registers
    const float4* xr = (const float4*)(comb32 + (size_t)q * DIM);
    float4 xreg[3];
    #pragma unroll
    for (int k = 0; k < 3; ++k) xreg[k] = xr[l + 64 * k];

    float bestd = FLT_MAX;
    int bestc = 0x7fffffff;
    for (int e = 0; e < ns; e += 2) {
        const int c0 = s2c[w][e];
        const bool has1 = (e + 1 < ns);
        const int c1 = has1 ? s2c[w][e + 1] : c0;
        const float4* cr0 = (const float4*)(codebook + (size_t)c0 * DIM);
        const float4* cr1 = (const float4*)(codebook + (size_t)c1 * DIM);
        float dot0 = 0.0f, dot1 = 0.0f;
        #pragma unroll
        for (int k = 0; k < 3; ++k) {
            const float4 y0 = cr0[l + 64 * k];
            const float4 y1 = cr1[l + 64 * k];
            const float4 xk = xreg[k];
            dot0 = fmaf(xk.x, y0.x, fmaf(xk.y, y0.y, fmaf(xk.z, y0.z, fmaf(xk.w, y0.w, dot0))));
            dot1 = fmaf(xk.x, y1.x, fmaf(xk.y, y1.y, fmaf(xk.z, y1.z, fmaf(xk.w, y1.w, dot1))));
        }
        #pragma unroll
        for (int off = 1; off <= 32; off <<= 1) {   // bitwise-identical lanes
            dot0 += __shfl_xor(dot0, off);
            dot1 += __shfl_xor(dot1, off);
        }
        const float d0 = fmaf(-2.0f, dot0, csq[c0]);
        if (d0 < bestd || (d0 == bestd && c0 < bestc)) { bestd = d0; bestc = c0; }
        if (has1) {
            const float d1 = fmaf(-2.0f, dot1, csq[c1]);
            if (d1 < bestd || (d1 == bestd && c1 < bestc)) { bestd = d1; bestc = c1; }
        }
    }
    if (l == 0) out_tok_f[q] = (float)bestc;
    const float4* cr = (const float4*)(codebook + (size_t)bestc * DIM);
    float4* o4 = (float4*)(out_q + (size_t)q * DIM);
    #pragma unroll
    for (int k = 0; k < 3; ++k) o4[l + 64 * k] = cr[l + 64 * k];
}

// ===========================================================================
// FALLBACK PATH (R2, proven): used only if ws_size is too small.
// ===========================================================================
__global__ __launch_bounds__(256) void argmin_mfma_kernel(
    const float* __restrict__ comb, const float* __restrict__ codebook,
    const short* __restrict__ cbb, const float* __restrict__ csq,
    float* __restrict__ out_tok_f, int* __restrict__ tok_i)
{
    __shared__ int s_cnt[QB];
    __shared__ int s_cand[QB][CAP];

    const int t = threadIdx.x;
    const int w = t >> 6;
    const int l = t & 63;
    const int lm = l & 15;
    const int quad = l >> 4;
    const int q0 = blockIdx.x * QB;

    for (int i = t; i < QB; i += 256) s_cnt[i] = 0;
    __syncthreads();

    bf16x8 a_reg[24];
    {
        const int qa = q0 + w * 16 + lm;
        const float* ap = comb + (size_t)qa * DIM + quad * 8;
        #pragma unroll
        for (int kc = 0; kc < 24; ++kc) {
            const float4 lo = *(const float4*)(ap + kc * 32);
            const float4 hi = *(const float4*)(ap + kc * 32 + 4);
            bf16x8 f;
            f[0] = f2b(lo.x); f[1] = f2b(lo.y); f[2] = f2b(lo.z); f[3] = f2b(lo.w);
            f[4] = f2b(hi.x); f[5] = f2b(hi.y); f[6] = f2b(hi.z); f[7] = f2b(hi.w);
            a_reg[kc] = f;
        }
    }

    const short* bp = cbb + (size_t)lm * DIM + quad * 8;
    float runmin[4] = {FLT_MAX, FLT_MAX, FLT_MAX, FLT_MAX};

    for (int chunk = 0; chunk < VOCABN / 64; ++chunk) {
        const int c0 = chunk * 64;
        const short* bc = bp + (size_t)c0 * DIM;
        f32x4 acc[4];
        #pragma unroll
        for (int s = 0; s < 4; ++s) acc[s] = (f32x4){0.f, 0.f, 0.f, 0.f};

        #pragma unroll
        for (int kc = 0; kc < 24; ++kc) {
            const bf16x8 a = a_reg[kc];
            #pragma unroll
            for (int s = 0; s < 4; ++s) {
                const bf16x8 b = *(const bf16x8*)(bc + s * 16 * DIM + kc * 32);
                acc[s] = __builtin_amdgcn_mfma_f32_16x16x32_bf16(a, b, acc[s], 0, 0, 0);
            }
        }

        float d[4][4];
        float m[4] = {FLT_MAX, FLT_MAX, FLT_MAX, FLT_MAX};
        #pragma unroll
        for (int s = 0; s < 4; ++s) {
            const float csv = csq[c0 + s * 16 + lm];
            #pragma unroll
            for (int r = 0; r < 4; ++r) {
                d[s][r] = fmaf(-2.0f, acc[s][r], csv);
                m[r] = fminf(m[r], d[s][r]);
            }
        }
        #pragma unroll
        for (int r = 0; r < 4; ++r) {
            float vv = m[r];
            vv = fminf(vv, __shfl_xor(vv, 1));
            vv = fminf(vv, __shfl_xor(vv, 2));
            vv = fminf(vv, __shfl_xor(vv, 4));
            vv = fminf(vv, __shfl_xor(vv, 8));
            runmin[r] = fminf(runmin[r], vv);
        }
        #pragma unroll
        for (int s = 0; s < 4; ++s) {
            #pragma unroll
            for (int r = 0; r < 4; ++r) {
                if (d[s][r] <= runmin[r] + MARGIN) {
                    const int qloc = w * 16 + quad * 4 + r;
                    const int idx = atomicAdd(&s_cnt[qloc], 1);
                    if (idx < CAP) s_cand[qloc][idx] = c0 + s * 16 + lm;
                }
            }
        }
    }
    __syncthreads();

    const int qloc = t >> 2;
    const int sub = t & 3;
    const int qg = q0 + qloc;
    int n = s_cnt[qloc];
    if (n > CAP) n = CAP;
    float bestd = FLT_MAX;
    int bestc = 0x7fffffff;
    const float4* xr = (const float4*)(comb + (size_t)qg * DIM);
    for (int i = 0; i < n; ++i) {
        const int c = s_cand[qloc][i];
        const float4* cr = (const float4*)(codebook + (size_t)c * DIM);
        float dot = 0.0f;
        #pragma unroll 4
        for (int j = sub * 48; j < sub * 48 + 48; ++j) {
            const float4 x = xr[j];
            const float4 y = cr[j];
            dot = fmaf(x.x, y.x, fmaf(x.y, y.y, fmaf(x.z, y.z, fmaf(x.w, y.w, dot))));
        }
        dot += __shfl_xor(dot, 1);
        dot += __shfl_xor(dot, 2);
        const float dist = fmaf(-2.0f, dot, csq[c]);
        if (dist < bestd || (dist == bestd && c < bestc)) { bestd = dist; bestc = c; }
    }
    if (sub == 0) {
        out_tok_f[qg] = (float)bestc;
        tok_i[qg] = bestc;
    }
}

__global__ __launch_bounds__(192) void gather_kernel(
    const int* __restrict__ tok, const float* __restrict__ codebook,
    float* __restrict__ outq)
{
    const int row = blockIdx.x;
    const int t = threadIdx.x;
    const int token = tok[row];
    const float4* cb4 = (const float4*)(codebook + (size_t)token * DIM);
    float4* o4 = (float4*)(outq + (size_t)row * DIM);
    o4[t] = cb4[t];
}

// ===========================================================================
extern "C" void kernel_launch(void* const* d_in, const int* in_sizes, int n_in,
                              void* d_out, int out_size, void* d_ws, size_t ws_size,
                              hipStream_t stream) {
    const float* coords   = (const float*)d_in[0];
    const float* feats    = (const float*)d_in[1];
    const float* Ws1      = (const float*)d_in[2];
    const float* bs1      = (const float*)d_in[3];
    const float* Ws2      = (const float*)d_in[4];
    const float* bs2      = (const float*)d_in[5];
    const float* Wf1      = (const float*)d_in[6];
    const float* bf1      = (const float*)d_in[7];
    const float* Wf2      = (const float*)d_in[8];
    const float* bf2      = (const float*)d_in[9];
    const float* codebook = (const float*)d_in[10];

    float* out = (float*)d_out;            // [32768 tokens][25165824 quantized]
    float* out_tok = out;
    float* out_q   = out + M_ROWS;

    const size_t SZ_COMB32 = (size_t)M_ROWS * DIM * 4;          // 100.66 MB
    const size_t SZ_COMB16 = (size_t)M_ROWS * DIM * 2;          //  50.33 MB
    const size_t SZ_CBB    = (size_t)VOCABN * DIM * 2;          //   6.29 MB
    const size_t SZ_CSQ    = (size_t)VOCABN * 4;
    const size_t SZ_LMIN   = (size_t)M_ROWS * NCB * 4;          //   4 MB
    const size_t SZ_LCI    = (size_t)M_ROWS * NCB * CAP2 * 4;   //  25 MB
    const size_t NEED = SZ_COMB32 + SZ_COMB16 + SZ_CBB + SZ_CSQ +
                        3 * SZ_LMIN + SZ_LCI;                   // ~198 MB

    char* p = (char*)d_ws;
    float* comb32 = (float*)p;              p += SZ_COMB32;
    short* comb16f = (short*)p;             p += SZ_COMB16;   // fragment order
    short* cbx = (short*)p;                 p += SZ_CBB;      // frag (main) / row (fb)
    float* csq = (float*)p;                 p += SZ_CSQ;

    if (ws_size >= NEED) {
        float* lmin_g = (float*)p;          p += SZ_LMIN;
        int*   lbidx_g = (int*)p;           p += SZ_LMIN;
        int*   lcnt_g = (int*)p;            p += SZ_LMIN;
        int*   lci_g = (int*)p;             p += SZ_LCI;

        encode_kernel<<<M_ROWS / 32, 256, 0, stream>>>(
            coords, feats, Ws1, bs1, Ws2, bs2, Wf1, bf1, Wf2, bf2,
            comb32, comb16f, 1);
        csq_cvt_kernel<<<VOCABN, 64, 0, stream>>>(codebook, csq, cbx, 1);
        dim3 g1(NCB, M_ROWS / BM1, 1);      // (32, 256)
        vq_phase1_kernel<<<g1, 256, 0, stream>>>(
            comb16f, cbx, csq, lmin_g, lbidx_g, lcnt_g, lci_g);
        vq_phase2_kernel<<<M_ROWS / 4, 256, 0, stream>>>(
            comb32, codebook, csq, lmin_g, lbidx_g, lcnt_g, lci_g,
            out_tok, out_q);
    } else {
        // R2 fallback: comb32 + cbb(row-major) + csq + toki
        int* toki = (int*)p;
        encode_kernel<<<M_ROWS / 32, 256, 0, stream>>>(
            coords, feats, Ws1, bs1, Ws2, bs2, Wf1, bf1, Wf2, bf2,
            comb32, comb16f, 0);
        csq_cvt_kernel<<<VOCABN, 64, 0, stream>>>(codebook, csq, cbx, 0);
        argmin_mfma_kernel<<<M_ROWS / QB, 256, 0, stream>>>(
            comb32, codebook, cbx, csq, out_tok, toki);
        gather_kernel<<<M_ROWS, 192, 0, stream>>>(toki, codebook, out_q);
    }
}